// Round 7
// baseline (4960.452 us; speedup 1.0000x reference)
//
#include <hip/hip_runtime.h>
#include <stdint.h>

typedef _Float16 half8 __attribute__((ext_vector_type(8)));
typedef float f32x4 __attribute__((ext_vector_type(4)));

#define NSTEP 48
#define MT 16
#define LDXF 260   // fp32 x row stride (words): start banks (4r+8q)%32 -> 8 lanes/bank, b128-optimal
#define LDH0 296   // h0 + ext(sn+zeros) row stride (halfs)
#define LDH1 264

// LDS-only barrier: does NOT drain vmcnt -> weight prefetch stays in flight.
#define BAR() do { asm volatile("s_waitcnt lgkmcnt(0)" ::: "memory"); \
                   __builtin_amdgcn_s_barrier();                      \
                   __builtin_amdgcn_sched_barrier(0); } while (0)

// Counted-vmcnt barrier: keeps the 16 newest weight loads in flight but
// guarantees the step-top x/cond DMAs (issued >100 loads earlier) have landed.
#define BAR_VM() do { asm volatile("s_waitcnt vmcnt(16) lgkmcnt(0)" ::: "memory"); \
                      __builtin_amdgcn_s_barrier();                                \
                      __builtin_amdgcn_sched_barrier(0); } while (0)

// global -> LDS DMA. LDS dest is wave-uniform base; lane l lands at base + l*size.
// AS3 value = low 32 bits of the generic LDS pointer (int-cast sidesteps addrspace casts).
#define GLDS(gp_, lp_, sz_) __builtin_amdgcn_global_load_lds(                      \
    (const __attribute__((address_space(1))) unsigned int*)(uintptr_t)(gp_),       \
    (__attribute__((address_space(3))) unsigned int*)(unsigned int)(uintptr_t)(lp_), \
    sz_, 0, 0)

__device__ __forceinline__ float sigm(float x) { return 1.0f / (1.0f + __expf(-x)); }
__device__ __forceinline__ float tanh_f(float x) {
  float ax = fabsf(x);
  float e = __expf(-2.0f * ax);
  float t = (1.0f - e) / (1.0f + e);
  return copysignf(t, x);
}

// Unified fragment-order packed weights, per-wave contiguous:
//   Wp[w][t(33)][c(4)][lane(64)=(q<<4|r)][j(8)]
//   t=0..16  : layer-0 K-tiles over K-layout [256 x | 256 h0 | 3 sn | 29 zeros]
//   t=17..32 : layer-1 K-tiles over K-layout [256 h0new | 256 h1]
__global__ void prep_weights(const float* __restrict__ Wih0, const float* __restrict__ Whh0,
                             const float* __restrict__ bih0, const float* __restrict__ bhh0,
                             const float* __restrict__ Wih1, const float* __restrict__ Whh1,
                             const float* __restrict__ bih1, const float* __restrict__ bhh1,
                             _Float16* __restrict__ Wp,
                             float* __restrict__ b0, float* __restrict__ b1) {
  int n = blockIdx.x;              // gate-row 0..1023
  int c = n >> 8, u = n & 255, w = u >> 4, r = u & 15;
  for (int k = threadIdx.x; k < 544; k += 256) {
    int t = k >> 5, kk = k & 31, q = kk >> 3, j = kk & 7;
    float val;
    if (k < 256) val = Wih0[n * 259 + k];
    else if (k < 512) val = Whh0[n * 256 + (k - 256)];
    else if (k < 515) val = Wih0[n * 259 + 256 + (k - 512)];
    else val = 0.0f;
    Wp[(((size_t)w * 33 + t) * 4 + c) * 512 + (size_t)(q * 16 + r) * 8 + j] = (_Float16)val;
  }
  for (int k = threadIdx.x; k < 512; k += 256) {
    int t = 17 + (k >> 5), kk = k & 31, q = kk >> 3, j = kk & 7;
    float val = (k < 256) ? Wih1[n * 256 + k] : Whh1[n * 256 + (k - 256)];
    Wp[(((size_t)w * 33 + t) * 4 + c) * 512 + (size_t)(q * 16 + r) * 8 + j] = (_Float16)val;
  }
  if (threadIdx.x == 0) { b0[n] = bih0[n] + bhh0[n]; b1[n] = bih1[n] + bhh1[n]; }
}

// 16 waves per WG (1 WG/CU; HARD budget 128 regs/wave total). All long-lived
// broadcast state lives in LDS; x/cond staged by global_load_lds DMA (zero regs).
// 33 weight K-tiles/step through two statically-named quad-buffers, prefetch
// crossing lgkm-only barriers; vmcnt never drained inside the loop (BAR_VM
// waits vmcnt(16): DMAs guaranteed, newest 2 weight tiles stay in flight).
__global__ __launch_bounds__(1024, 4)
void noteaxis_main(const float* __restrict__ nf, const float* __restrict__ cond,
                   const _Float16* __restrict__ Wp,
                   const float* __restrict__ b0g, const float* __restrict__ b1g,
                   const float* __restrict__ Wout, const float* __restrict__ bout,
                   float* __restrict__ out) {
  __shared__ __align__(16) float lds_xf[2][MT][LDXF];
  __shared__ __align__(16) _Float16 lds_h0[MT][LDH0];
  __shared__ __align__(16) _Float16 lds_h1[MT][LDH1];
  __shared__ float lds_part[16][MT][3];
  __shared__ float lds_b0[1024], lds_b1[1024];
  __shared__ float lds_wo[768];
  __shared__ float lds_sn[MT * 3];

  const int tid = threadIdx.x;
  const int w = tid >> 6;        // wave 0..15: unit slice
  const int lane = tid & 63;
  const int r = lane & 15;       // A row = batch row; D col = unit-within-slice
  const int q = lane >> 4;       // k sub-chunk / D row group
  const int u = w * 16 + r;      // this lane's unit column
  const int row0 = blockIdx.x * MT;

  for (int i = tid; i < MT * LDH0; i += 1024) ((_Float16*)lds_h0)[i] = (_Float16)0.0f;
  for (int i = tid; i < MT * LDH1; i += 1024) ((_Float16*)lds_h1)[i] = (_Float16)0.0f;
  lds_b0[tid] = b0g[tid];
  lds_b1[tid] = b1g[tid];
  if (tid < 768) lds_wo[tid] = Wout[tid];
  const float bo0 = bout[0], bo1 = bout[1], bo2 = bout[2];   // uniform -> SGPRs

  float c0s[4], c1s[4];
#pragma unroll
  for (int g = 0; g < 4; ++g) { c0s[g] = 0.0f; c1s[g] = 0.0f; }

  f32x4 acc[4];
  half8 QA[4], QB[4];            // statically-named depth-2 quad-buffers

#define LOADT(BUF_, P_) do {                                                       \
    BUF_[0] = *(const half8*)(P_);                                                 \
    BUF_[1] = *(const half8*)((P_) + 512);                                         \
    BUF_[2] = *(const half8*)((P_) + 1024);                                        \
    BUF_[3] = *(const half8*)((P_) + 1536);                                        \
  } while (0)

#define MFMAQ(BUF_, a_) do {                                                         \
    acc[0] = __builtin_amdgcn_mfma_f32_16x16x32_f16((a_), BUF_[0], acc[0], 0, 0, 0); \
    acc[1] = __builtin_amdgcn_mfma_f32_16x16x32_f16((a_), BUF_[1], acc[1], 0, 0, 0); \
    acc[2] = __builtin_amdgcn_mfma_f32_16x16x32_f16((a_), BUF_[2], acc[2], 0, 0, 0); \
    acc[3] = __builtin_amdgcn_mfma_f32_16x16x32_f16((a_), BUF_[3], acc[3], 0, 0, 0); \
  } while (0)

// x A-fragment from fp32 LDS (cvt at use; 8 tiles/step -> noise)
#define A0X(pb, t) __extension__({                                                 \
    float4 _lo = *(const float4*)&lds_xf[pb][r][(t) * 32 + q * 8];                 \
    float4 _hi = *(const float4*)&lds_xf[pb][r][(t) * 32 + q * 8 + 4];             \
    half8 _a;                                                                      \
    _a[0] = (_Float16)_lo.x; _a[1] = (_Float16)_lo.y;                              \
    _a[2] = (_Float16)_lo.z; _a[3] = (_Float16)_lo.w;                              \
    _a[4] = (_Float16)_hi.x; _a[5] = (_Float16)_hi.y;                              \
    _a[6] = (_Float16)_hi.z; _a[7] = (_Float16)_hi.w;                              \
    _a; })

#define A0F(pb, t) ((t) < 8  ? A0X(pb, t)                                          \
                  : (t) < 16 ? *(const half8*)&lds_h0[r][((t) - 8) * 32 + q * 8]   \
                             : *(const half8*)&lds_h0[r][256 + q * 8])
#define A1F(s) ((s) < 8  ? *(const half8*)&lds_h0[r][(s) * 32 + q * 8]             \
                         : *(const half8*)&lds_h1[r][((s) - 8) * 32 + q * 8])

#define P1T(pb, t, BUF_, P_) do { half8 _a = A0F(pb, t); MFMAQ(BUF_, _a); LOADT(BUF_, P_); P_ += 4096; } while (0)
#define P3T(s, BUF_, P_)     do { half8 _a = A1F(s);     MFMAQ(BUF_, _a); LOADT(BUF_, P_); P_ += 4096; } while (0)

// One note-step. Entry: QA_=tile0, QB_=tile1, PE_->tile2, PO_->tile3.
// Exit: same invariant with roles swapped -> call alternately.
#define STEPB(NN_, PB_, QA_, QB_, PE_, PO_) do {                                   \
    const int nn = (NN_);                                                          \
    { /* step-top DMAs: x(n+1) -> lds_xf[PB^1], cond slice(nn) -> lds_sn */        \
      const int np = (nn + 1 < NSTEP) ? nn + 1 : nn;                               \
      GLDS(nf + ((size_t)(row0 + w) * NSTEP + np) * 256 + lane * 4,                \
           &lds_xf[(PB_) ^ 1][w][0], 16);                                          \
      if (w == 0 && lane < MT * 3) {                                               \
        const int m_ = lane / 3, ch_ = lane - m_ * 3;                              \
        GLDS(cond + ((size_t)(row0 + m_) * NSTEP + nn) * 3 + ch_, &lds_sn[0], 4);  \
      }                                                                            \
    }                                                                              \
    _Pragma("unroll")                                                              \
    for (int c = 0; c < 4; ++c) {                                                  \
      float b_ = lds_b0[c * 256 + u];                                              \
      f32x4 bz = {b_, b_, b_, b_}; acc[c] = bz;                                    \
    }                                                                              \
    __builtin_amdgcn_s_setprio(1);                                                 \
    P1T(PB_, 0, QA_, PE_);  P1T(PB_, 1, QB_, PO_);                                 \
    P1T(PB_, 2, QA_, PE_);  P1T(PB_, 3, QB_, PO_);                                 \
    P1T(PB_, 4, QA_, PE_);  P1T(PB_, 5, QB_, PO_);                                 \
    P1T(PB_, 6, QA_, PE_);  P1T(PB_, 7, QB_, PO_);                                 \
    P1T(PB_, 8, QA_, PE_);  P1T(PB_, 9, QB_, PO_);                                 \
    P1T(PB_, 10, QA_, PE_); P1T(PB_, 11, QB_, PO_);                                \
    P1T(PB_, 12, QA_, PE_); P1T(PB_, 13, QB_, PO_);                                \
    P1T(PB_, 14, QA_, PE_); P1T(PB_, 15, QB_, PO_);                                \
    P1T(PB_, 16, QA_, PE_);                                                        \
    __builtin_amdgcn_s_setprio(0);                                                 \
    BAR_VM();  /* B1: lds_x/h0 reads done; cond-DMA (>>16 loads old) landed */     \
    _Pragma("unroll")                                                              \
    for (int g = 0; g < 4; ++g) {                                                  \
      float i_ = acc[0][g], f_ = acc[1][g], g_ = acc[2][g], o_ = acc[3][g];        \
      float cc = sigm(f_) * c0s[g] + sigm(i_) * tanh_f(g_);                        \
      c0s[g] = cc;                                                                 \
      lds_h0[q * 4 + g][u] = (_Float16)(sigm(o_) * tanh_f(cc));                    \
    }                                                                              \
    if (tid < MT * 3) {                                                            \
      int m_ = tid / 3, ch_ = tid - m_ * 3;                                        \
      lds_h0[m_][256 + ch_] = (_Float16)lds_sn[tid];                               \
    }                                                                              \
    if (nn > 0 && tid < MT * 3) {                                                  \
      int m_ = tid / 3, ch_ = tid - m_ * 3;                                        \
      float s_ = (ch_ == 0 ? bo0 : (ch_ == 1 ? bo1 : bo2));                        \
      _Pragma("unroll")                                                            \
      for (int ww = 0; ww < 16; ++ww) s_ += lds_part[ww][m_][ch_];                 \
      if (ch_ < 2) s_ = 1.0f / (1.0f + __expf(-s_));                               \
      out[((size_t)(row0 + m_) * NSTEP + (nn - 1)) * 3 + ch_] = s_;                \
    }                                                                              \
    BAR();  /* B2: h0(n), sn-ext visible */                                        \
    _Pragma("unroll")                                                              \
    for (int c = 0; c < 4; ++c) {                                                  \
      float b_ = lds_b1[c * 256 + u];                                              \
      f32x4 bz = {b_, b_, b_, b_}; acc[c] = bz;                                    \
    }                                                                              \
    __builtin_amdgcn_s_setprio(1);                                                 \
    P3T(0, QB_, PO_);  P3T(1, QA_, PE_);  P3T(2, QB_, PO_);  P3T(3, QA_, PE_);     \
    P3T(4, QB_, PO_);  P3T(5, QA_, PE_);  P3T(6, QB_, PO_);  P3T(7, QA_, PE_);     \
    P3T(8, QB_, PO_);  P3T(9, QA_, PE_);  P3T(10, QB_, PO_); P3T(11, QA_, PE_);    \
    P3T(12, QB_, PO_); P3T(13, QA_, PE_);                                          \
    { half8 _a = A1F(14); MFMAQ(QB_, _a); PO_ -= 33 * 2048; LOADT(QB_, PO_); PO_ += 4096; } \
    { half8 _a = A1F(15); MFMAQ(QA_, _a); PE_ -= 33 * 2048; LOADT(QA_, PE_); PE_ += 4096; } \
    __builtin_amdgcn_s_setprio(0);                                                 \
    BAR_VM();  /* B3: h0/h1 reads done; x-DMA landed; 2 weight tiles in flight */  \
    {                                                                              \
      float wv0 = lds_wo[u], wv1 = lds_wo[256 + u], wv2 = lds_wo[512 + u];         \
      float part[4][3];                                                            \
      _Pragma("unroll")                                                            \
      for (int g = 0; g < 4; ++g) {                                                \
        float i_ = acc[0][g], f_ = acc[1][g], g_ = acc[2][g], o_ = acc[3][g];      \
        float cc = sigm(f_) * c1s[g] + sigm(i_) * tanh_f(g_);                      \
        c1s[g] = cc;                                                               \
        float hh = sigm(o_) * tanh_f(cc);                                          \
        lds_h1[q * 4 + g][u] = (_Float16)hh;                                       \
        part[g][0] = hh * wv0;                                                     \
        part[g][1] = hh * wv1;                                                     \
        part[g][2] = hh * wv2;                                                     \
      }                                                                            \
      _Pragma("unroll")                                                            \
      for (int g = 0; g < 4; ++g) {                                                \
        _Pragma("unroll")                                                          \
        for (int ch = 0; ch < 3; ++ch) {                                           \
          float p = part[g][ch];                                                   \
          p += __shfl_xor(p, 1);                                                   \
          p += __shfl_xor(p, 2);                                                   \
          p += __shfl_xor(p, 4);                                                   \
          p += __shfl_xor(p, 8);                                                   \
          part[g][ch] = p;                                                         \
        }                                                                          \
      }                                                                            \
      if (r == 0) {                                                                \
        _Pragma("unroll")                                                          \
        for (int g = 0; g < 4; ++g) {                                              \
          int m_ = q * 4 + g;                                                      \
          lds_part[w][m_][0] = part[g][0];                                         \
          lds_part[w][m_][1] = part[g][1];                                         \
          lds_part[w][m_][2] = part[g][2];                                         \
        }                                                                          \
      }                                                                            \
    }                                                                              \
  } while (0)

  // prologue: DMA x(0) into buffer 0; __syncthreads drains vmcnt -> ready.
  GLDS(nf + ((size_t)(row0 + w) * NSTEP + 0) * 256 + lane * 4, &lds_xf[0][w][0], 16);
  __syncthreads();

  const _Float16* pE = Wp + (size_t)w * (33 * 2048) + lane * 8;   // tile0
  const _Float16* pO = pE + 2048;                                 // tile1
  LOADT(QA, pE); pE += 4096;   // QA=tile0, pE->tile2
  LOADT(QB, pO); pO += 4096;   // QB=tile1, pO->tile3

#pragma unroll 1
  for (int n = 0; n < NSTEP; n += 2) {
    STEPB(n,     0, QA, QB, pE, pO);
    STEPB(n + 1, 1, QB, QA, pO, pE);
  }

  BAR();
  if (tid < MT * 3) {
    int m_ = tid / 3, ch_ = tid - m_ * 3;
    float s_ = (ch_ == 0 ? bo0 : (ch_ == 1 ? bo1 : bo2));
#pragma unroll
    for (int ww = 0; ww < 16; ++ww) s_ += lds_part[ww][m_][ch_];
    if (ch_ < 2) s_ = 1.0f / (1.0f + __expf(-s_));
    out[((size_t)(row0 + m_) * NSTEP + (NSTEP - 1)) * 3 + ch_] = s_;
  }
}

extern "C" void kernel_launch(void* const* d_in, const int* in_sizes, int n_in,
                              void* d_out, int out_size, void* d_ws, size_t ws_size,
                              hipStream_t stream) {
  const float* nf   = (const float*)d_in[0];
  const float* cond = (const float*)d_in[1];
  const float* Wih0 = (const float*)d_in[2];
  const float* Whh0 = (const float*)d_in[3];
  const float* bih0 = (const float*)d_in[4];
  const float* bhh0 = (const float*)d_in[5];
  const float* Wih1 = (const float*)d_in[6];
  const float* Whh1 = (const float*)d_in[7];
  const float* bih1 = (const float*)d_in[8];
  const float* bhh1 = (const float*)d_in[9];
  const float* Wout = (const float*)d_in[10];
  const float* bout = (const float*)d_in[11];
  float* out = (float*)d_out;

  _Float16* Wp = (_Float16*)d_ws;                  // 16*33*4*512 = 1081344 halfs
  float* b0 = (float*)(Wp + 16 * 33 * 4 * 512);    // 4 KB
  float* b1 = b0 + 1024;                           // 4 KB

  prep_weights<<<1024, 256, 0, stream>>>(Wih0, Whh0, bih0, bhh0, Wih1, Whh1, bih1, bhh1, Wp, b0, b1);
  noteaxis_main<<<256, 1024, 0, stream>>>(nf, cond, Wp, b0, b1, Wout, bout, out);
}

// Round 8
// 1730.198 us; speedup vs baseline: 2.8670x; 2.8670x over previous
//
#include <hip/hip_runtime.h>

typedef _Float16 half8 __attribute__((ext_vector_type(8)));
typedef _Float16 half4 __attribute__((ext_vector_type(4)));
typedef float f32x4 __attribute__((ext_vector_type(4)));

#define NSTEP 48
#define MT 32      // batch rows per workgroup: TWO 16-row groups sharing each B-tile load
#define LDX 264    // x row stride (halfs)
#define LDH0 296   // h0 + ext(sn+zeros) row stride
#define LDH1 264

__device__ __forceinline__ float sigm(float x) { return 1.0f / (1.0f + __expf(-x)); }
__device__ __forceinline__ float tanh_f(float x) {
  float ax = fabsf(x);
  float e = __expf(-2.0f * ax);
  float t = (1.0f - e) / (1.0f + e);
  return copysignf(t, x);
}

// Fragment-order packed weights (coalesced: one 1KB contiguous block per (w,kt,c)):
//   W0p[w][kt(17)][c(4)][lane(64)=(q<<4|r)][j(8)] = W0[c*256 + w*16 + r][kt*32 + q*8 + j]
//     where W0 K-layout = [256 x-feat | 256 h0 | 3 shifted-notes | 29 zeros]
//   W1p[w][kt(16)][c][lane][j] = W1[c*256 + w*16 + r][kt*32 + q*8 + j], K = [256 h0new | 256 h1]
__global__ void prep_weights(const float* __restrict__ Wih0, const float* __restrict__ Whh0,
                             const float* __restrict__ bih0, const float* __restrict__ bhh0,
                             const float* __restrict__ Wih1, const float* __restrict__ Whh1,
                             const float* __restrict__ bih1, const float* __restrict__ bhh1,
                             _Float16* __restrict__ W0p, _Float16* __restrict__ W1p,
                             float* __restrict__ b0, float* __restrict__ b1) {
  int n = blockIdx.x;              // gate-row 0..1023
  int c = n >> 8, u = n & 255, w = u >> 4, r = u & 15;
  for (int k = threadIdx.x; k < 544; k += 256) {
    int kt = k >> 5, kk = k & 31, q = kk >> 3, j = kk & 7;
    float val;
    if (k < 256) val = Wih0[n * 259 + k];
    else if (k < 512) val = Whh0[n * 256 + (k - 256)];
    else if (k < 515) val = Wih0[n * 259 + 256 + (k - 512)];
    else val = 0.0f;
    W0p[((((w * 17 + kt) * 4 + c) * 64) + q * 16 + r) * 8 + j] = (_Float16)val;
  }
  for (int k = threadIdx.x; k < 512; k += 256) {
    int kt = k >> 5, kk = k & 31, q = kk >> 3, j = kk & 7;
    float val = (k < 256) ? Wih1[n * 256 + k] : Whh1[n * 256 + (k - 256)];
    W1p[((((w * 16 + kt) * 4 + c) * 64) + q * 16 + r) * 8 + j] = (_Float16)val;
  }
  if (threadIdx.x == 0) { b0[n] = bih0[n] + bhh0[n]; b1[n] = bih1[n] + bhh1[n]; }
}

// 16 waves per WG. Wave w owns units [w*16, w*16+16) x all 4 gates, for BOTH
// 16-row batch groups (rows r and r+16): each B-tile register load feeds two
// MFMAs -> chip-wide weight stream halves (128 blocks x 2.1 MB vs 256 x 2.1 MB).
// Schedule/buffering identical to the proven R1 kernel (no cross-phase live
// prefetch; plain __syncthreads; Ba/Bc only -> no spill).
__global__ __launch_bounds__(1024, 4)
void noteaxis_main(const float* __restrict__ nf, const float* __restrict__ cond,
                   const _Float16* __restrict__ W0p, const _Float16* __restrict__ W1p,
                   const float* __restrict__ b0g, const float* __restrict__ b1g,
                   const float* __restrict__ Wout, const float* __restrict__ bout,
                   float* __restrict__ out) {
  __shared__ __align__(16) _Float16 lds_x[MT][LDX];
  __shared__ __align__(16) _Float16 lds_h0[MT][LDH0];
  __shared__ __align__(16) _Float16 lds_h1[MT][LDH1];
  __shared__ float lds_part[16][MT][3];
  __shared__ float lds_b0[1024], lds_b1[1024];

  const int tid = threadIdx.x;
  const int w = tid >> 6;        // wave 0..15: unit slice
  const int lane = tid & 63;
  const int r = lane & 15;       // A row within group; D col = unit-within-slice
  const int q = lane >> 4;       // k sub-chunk / D row group
  const int u = w * 16 + r;      // this lane's unit column
  const int row0 = blockIdx.x * MT;

  for (int i = tid; i < MT * LDH0; i += 1024) ((_Float16*)lds_h0)[i] = (_Float16)0.0f;
  for (int i = tid; i < MT * LDH1; i += 1024) ((_Float16*)lds_h1)[i] = (_Float16)0.0f;
  lds_b0[tid] = b0g[tid];
  lds_b1[tid] = b1g[tid];

  const float wov0 = Wout[u], wov1 = Wout[256 + u], wov2 = Wout[512 + u];
  const float bo0 = bout[0], bo1 = bout[1], bo2 = bout[2];

  float c0sA[4], c0sB[4], c1sA[4], c1sB[4];
#pragma unroll
  for (int g = 0; g < 4; ++g) { c0sA[g] = 0.0f; c0sB[g] = 0.0f; c1sA[g] = 0.0f; c1sB[g] = 0.0f; }

  const _Float16* pW0 = W0p + (size_t)w * (17 * 4 * 512) + lane * 8;
  const _Float16* pW1 = W1p + (size_t)w * (16 * 4 * 512) + lane * 8;

  f32x4 accA[4], accB[4];        // group0 / group1 accumulators (AGPR side)
  half8 Ba[4], Bc[4];            // the R1-proven two-buffer shape

  auto loadW = [&](half8* d, const _Float16* base, int ktc4) {
#pragma unroll
    for (int c = 0; c < 4; ++c) d[c] = *(const half8*)(base + (ktc4 + c) * 512);
  };
  // one B-buffer feeds BOTH row groups
  auto mfmaD = [&](half8 aA, half8 aB, const half8* B) {
#pragma unroll
    for (int c = 0; c < 4; ++c) {
      accA[c] = __builtin_amdgcn_mfma_f32_16x16x32_f16(aA, B[c], accA[c], 0, 0, 0);
      accB[c] = __builtin_amdgcn_mfma_f32_16x16x32_f16(aB, B[c], accB[c], 0, 0, 0);
    }
  };

  __syncthreads();

#pragma unroll 1
  for (int n = 0; n < NSTEP; ++n) {
    // ---- stage x(n) (two rows per wave) + shifted notes ----
    {
      const float4 xa = *(const float4*)(nf + ((size_t)(row0 + w) * NSTEP + n) * 256 + lane * 4);
      const float4 xb = *(const float4*)(nf + ((size_t)(row0 + 16 + w) * NSTEP + n) * 256 + lane * 4);
      half4 ha = { (_Float16)xa.x, (_Float16)xa.y, (_Float16)xa.z, (_Float16)xa.w };
      half4 hb = { (_Float16)xb.x, (_Float16)xb.y, (_Float16)xb.z, (_Float16)xb.w };
      *(half4*)&lds_x[w][lane * 4] = ha;
      *(half4*)&lds_x[16 + w][lane * 4] = hb;
    }
    if (tid < MT) {
      float s0 = 0.f, s1 = 0.f, s2 = 0.f;
      if (n > 0) {
        const float* cp = cond + ((size_t)(row0 + tid) * NSTEP + (n - 1)) * 3;
        s0 = cp[0]; s1 = cp[1]; s2 = cp[2];
      }
      lds_h0[tid][256] = (_Float16)s0;
      lds_h0[tid][257] = (_Float16)s1;
      lds_h0[tid][258] = (_Float16)s2;
    }
    __syncthreads();  // B0

    // acc init = bias0 (both groups)
#pragma unroll
    for (int c = 0; c < 4; ++c) {
      float b = lds_b0[c * 256 + u];
      f32x4 bz = {b, b, b, b};
      accA[c] = bz; accB[c] = bz;
    }

    // ================= Layer 0 =================
#pragma unroll 2
    for (int kt = 0; kt < 8; kt += 2) {          // x part (kt 0..7)
      loadW(Ba, pW0, kt * 4);
      loadW(Bc, pW0, kt * 4 + 4);
      mfmaD(*(const half8*)&lds_x[r][kt * 32 + q * 8],
            *(const half8*)&lds_x[16 + r][kt * 32 + q * 8], Ba);
      mfmaD(*(const half8*)&lds_x[r][kt * 32 + 32 + q * 8],
            *(const half8*)&lds_x[16 + r][kt * 32 + 32 + q * 8], Bc);
    }
#pragma unroll 2
    for (int kt = 0; kt < 8; kt += 2) {          // h0 part (weight kt 8..15)
      loadW(Ba, pW0, 32 + kt * 4);
      loadW(Bc, pW0, 32 + kt * 4 + 4);
      mfmaD(*(const half8*)&lds_h0[r][kt * 32 + q * 8],
            *(const half8*)&lds_h0[16 + r][kt * 32 + q * 8], Ba);
      mfmaD(*(const half8*)&lds_h0[r][kt * 32 + 32 + q * 8],
            *(const half8*)&lds_h0[16 + r][kt * 32 + 32 + q * 8], Bc);
    }
    loadW(Ba, pW0, 64);                          // ext part: [sn | zeros] (weight kt 16)
    mfmaD(*(const half8*)&lds_h0[r][256 + q * 8],
          *(const half8*)&lds_h0[16 + r][256 + q * 8], Ba);

    __syncthreads();  // B1: all waves done reading lds_x / lds_h0(n-1)

    // ---- cell 0 (both groups) ----
#pragma unroll
    for (int g = 0; g < 4; ++g) {
      float iA = accA[0][g], fA = accA[1][g], gA = accA[2][g], oA = accA[3][g];
      float ccA = sigm(fA) * c0sA[g] + sigm(iA) * tanh_f(gA);
      c0sA[g] = ccA;
      lds_h0[q * 4 + g][u] = (_Float16)(sigm(oA) * tanh_f(ccA));
      float iB = accB[0][g], fB = accB[1][g], gB = accB[2][g], oB = accB[3][g];
      float ccB = sigm(fB) * c0sB[g] + sigm(iB) * tanh_f(gB);
      c0sB[g] = ccB;
      lds_h0[16 + q * 4 + g][u] = (_Float16)(sigm(oB) * tanh_f(ccB));
    }
    __syncthreads();  // B2: h0(n) visible

    // acc init = bias1 (both groups)
#pragma unroll
    for (int c = 0; c < 4; ++c) {
      float b = lds_b1[c * 256 + u];
      f32x4 bz = {b, b, b, b};
      accA[c] = bz; accB[c] = bz;
    }

    // ================= Layer 1 =================
#pragma unroll 2
    for (int kt = 0; kt < 8; kt += 2) {          // h0new part
      loadW(Ba, pW1, kt * 4);
      loadW(Bc, pW1, kt * 4 + 4);
      mfmaD(*(const half8*)&lds_h0[r][kt * 32 + q * 8],
            *(const half8*)&lds_h0[16 + r][kt * 32 + q * 8], Ba);
      mfmaD(*(const half8*)&lds_h0[r][kt * 32 + 32 + q * 8],
            *(const half8*)&lds_h0[16 + r][kt * 32 + 32 + q * 8], Bc);
    }
#pragma unroll 2
    for (int kt = 0; kt < 8; kt += 2) {          // h1 part (weight kt 8..15)
      loadW(Ba, pW1, 32 + kt * 4);
      loadW(Bc, pW1, 32 + kt * 4 + 4);
      mfmaD(*(const half8*)&lds_h1[r][kt * 32 + q * 8],
            *(const half8*)&lds_h1[16 + r][kt * 32 + q * 8], Ba);
      mfmaD(*(const half8*)&lds_h1[r][kt * 32 + 32 + q * 8],
            *(const half8*)&lds_h1[16 + r][kt * 32 + 32 + q * 8], Bc);
    }

    __syncthreads();  // B3: all waves done reading lds_h0(n)/lds_h1(n-1)

    // ---- cell 1 + output partials, group A then group B (bounded liveness) ----
#pragma unroll
    for (int grp = 0; grp < 2; ++grp) {
      float part[4][3];
#pragma unroll
      for (int g = 0; g < 4; ++g) {
        float i_, f_, g_, o_, cprev;
        if (grp == 0) { i_ = accA[0][g]; f_ = accA[1][g]; g_ = accA[2][g]; o_ = accA[3][g]; cprev = c1sA[g]; }
        else          { i_ = accB[0][g]; f_ = accB[1][g]; g_ = accB[2][g]; o_ = accB[3][g]; cprev = c1sB[g]; }
        float cc = sigm(f_) * cprev + sigm(i_) * tanh_f(g_);
        if (grp == 0) c1sA[g] = cc; else c1sB[g] = cc;
        float hh = sigm(o_) * tanh_f(cc);
        lds_h1[grp * 16 + q * 4 + g][u] = (_Float16)hh;
        part[g][0] = hh * wov0;
        part[g][1] = hh * wov1;
        part[g][2] = hh * wov2;
      }
#pragma unroll
      for (int g = 0; g < 4; ++g)
#pragma unroll
        for (int ch = 0; ch < 3; ++ch) {
          float p = part[g][ch];
          p += __shfl_xor(p, 1);
          p += __shfl_xor(p, 2);
          p += __shfl_xor(p, 4);
          p += __shfl_xor(p, 8);
          part[g][ch] = p;
        }
      if (r == 0) {
#pragma unroll
        for (int g = 0; g < 4; ++g) {
          int m = grp * 16 + q * 4 + g;
          lds_part[w][m][0] = part[g][0];
          lds_part[w][m][1] = part[g][1];
          lds_part[w][m][2] = part[g][2];
        }
      }
    }
    __syncthreads();  // B4

    if (tid < MT * 3) {
      int m = tid / 3;
      int ch = tid - m * 3;
      float s = lds_part[0][m][ch];
#pragma unroll
      for (int ww = 1; ww < 16; ++ww) s += lds_part[ww][m][ch];
      s += (ch == 0 ? bo0 : (ch == 1 ? bo1 : bo2));
      if (ch < 2) s = 1.0f / (1.0f + __expf(-s));
      out[((size_t)(row0 + m) * NSTEP + n) * 3 + ch] = s;
    }
  }
}

extern "C" void kernel_launch(void* const* d_in, const int* in_sizes, int n_in,
                              void* d_out, int out_size, void* d_ws, size_t ws_size,
                              hipStream_t stream) {
  const float* nf   = (const float*)d_in[0];
  const float* cond = (const float*)d_in[1];
  const float* Wih0 = (const float*)d_in[2];
  const float* Whh0 = (const float*)d_in[3];
  const float* bih0 = (const float*)d_in[4];
  const float* bhh0 = (const float*)d_in[5];
  const float* Wih1 = (const float*)d_in[6];
  const float* Whh1 = (const float*)d_in[7];
  const float* bih1 = (const float*)d_in[8];
  const float* bhh1 = (const float*)d_in[9];
  const float* Wout = (const float*)d_in[10];
  const float* bout = (const float*)d_in[11];
  float* out = (float*)d_out;

  _Float16* W0p = (_Float16*)d_ws;                 // 16*17*4*512 = 557056 halfs
  _Float16* W1p = W0p + 16 * 17 * 4 * 512;         // 16*16*4*512 = 524288 halfs
  float* b0 = (float*)(W1p + 16 * 16 * 4 * 512);   // 4 KB
  float* b1 = b0 + 1024;                           // 4 KB

  prep_weights<<<1024, 256, 0, stream>>>(Wih0, Whh0, bih0, bhh0, Wih1, Whh1, bih1, bhh1, W0p, W1p, b0, b1);
  noteaxis_main<<<128, 1024, 0, stream>>>(nf, cond, W0p, W1p, b0, b1, Wout, bout, out);
}